// Round 3
// baseline (673.037 us; speedup 1.0000x reference)
//
#include <hip/hip_runtime.h>
#include <hip/hip_bf16.h>

#define NODELEN 17949
#define NN 512
#define NE 4096
#define H2 768
#define EMB 128
#define IN_DIM (2 * NODELEN)      // 35898
#define KX 17984                  // NODELEN padded to 64 (281*64)
#define NKI 281                   // KX/64
#define NZ 1536                   // 2*H2
#define SPLITS 16
#define KCHUNK 18                 // ceil(281/16)

#define BM 128
#define BN 128
#define BK 64
#define LDT (BK + 8)

typedef __bf16 bf16x8 __attribute__((ext_vector_type(8)));
typedef float f32x4 __attribute__((ext_vector_type(4)));

// ---------------- graph prep (dense adjacency) ----------------

__global__ void k_zero_int(int* p, int n) {
    int i = blockIdx.x * 256 + threadIdx.x;
    if (i < n) p[i] = 0;
}

__global__ void k_zero_f4(float4* p, int n4) {
    int i = blockIdx.x * 256 + threadIdx.x;
    if (i < n4) p[i] = make_float4(0.f, 0.f, 0.f, 0.f);
}

__global__ void k_deg(const int* __restrict__ dst, int* __restrict__ cnt) {
    int e = blockIdx.x * 256 + threadIdx.x;
    if (e < NE) atomicAdd(&cnt[dst[e]], 1);
}

__global__ void k_invdeg(const int* __restrict__ cnt, float* __restrict__ invdeg) {
    int i = blockIdx.x * 256 + threadIdx.x;
    if (i < NN) {
        int c = cnt[i];
        invdeg[i] = 1.0f / (float)(c > 1 ? c : 1);
    }
}

// A[dst][src] += 1/deg[dst]
__global__ void k_scatter(const int* __restrict__ src, const int* __restrict__ dst,
                          const float* __restrict__ invdeg, float* __restrict__ A) {
    int e = blockIdx.x * 256 + threadIdx.x;
    if (e < NE) {
        int d = dst[e];
        atomicAdd(&A[(size_t)d * NN + src[e]], invdeg[d]);
    }
}

// A2 = A @ A (fp32), row-sparsity skip (uniform branch on broadcast value)
__global__ void k_a2f(const float* __restrict__ A, float* __restrict__ A2) {
    int i = blockIdx.x;
    int t = threadIdx.x;   // 256
    __shared__ float row[NN];
    row[t] = A[(size_t)i * NN + t];
    row[t + 256] = A[(size_t)i * NN + 256 + t];
    __syncthreads();
    float a0 = 0.f, a1 = 0.f;
    for (int s = 0; s < NN; ++s) {
        float a = row[s];
        if (a != 0.f) {
            a0 += a * A[(size_t)s * NN + t];
            a1 += a * A[(size_t)s * NN + 256 + t];
        }
    }
    A2[(size_t)i * NN + t] = a0;
    A2[(size_t)i * NN + 256 + t] = a1;
}

// xb[n][k] = bf16(x[n][k]), col0 zero, k>=NODELEN zero-pad
__global__ void k_xb(const float* __restrict__ x, __bf16* __restrict__ xb) {
    size_t idx = (size_t)blockIdx.x * 256 + threadIdx.x;
    if (idx >= (size_t)NN * KX) return;
    int n = (int)(idx / KX), k = (int)(idx % KX);
    float v = (k == 0 || k >= NODELEN) ? 0.f : x[(size_t)n * NODELEN + k];
    xb[idx] = (__bf16)v;
}

// Wb[n][k]: n<H2 -> W_e2[n][k] (W_L); n>=H2 -> W_e2[n-H2][NODELEN+k] (W_R); pad 0
__global__ void k_wb(const float* __restrict__ W, __bf16* __restrict__ Wb) {
    size_t idx = (size_t)blockIdx.x * 256 + threadIdx.x;
    if (idx >= (size_t)NZ * KX) return;
    int n = (int)(idx / KX), k = (int)(idx % KX);
    float v = 0.f;
    if (k < NODELEN) {
        int r = n, c = k;
        if (n >= H2) { r = n - H2; c = k + NODELEN; }
        v = W[(size_t)r * IN_DIM + c];
    }
    Wb[idx] = (__bf16)v;
}

// ---------------- split-K MFMA GEMM: partials[z][m][n] = sum_k A[m][k]*B[n][k] ----------------

__global__ __launch_bounds__(256) void gemm_splitk(
        const __bf16* __restrict__ A, const __bf16* __restrict__ B,
        float* __restrict__ partials) {
    __shared__ __align__(16) __bf16 As[BM][LDT];
    __shared__ __align__(16) __bf16 Bs[BN][LDT];

    const int tid = threadIdx.x;
    const int m0 = blockIdx.x * BM;
    const int n0 = blockIdx.y * BN;
    const int z = blockIdx.z;

    int it0 = z * KCHUNK;
    int it1 = it0 + KCHUNK;
    if (it1 > NKI) it1 = NKI;

    const int wave = tid >> 6;
    const int lane = tid & 63;
    const int wm = (wave & 1) * 64;
    const int wn = (wave >> 1) * 64;
    const int fl = lane & 15;
    const int fq = lane >> 4;

    const int srow = tid >> 1;
    const int spart = tid & 1;

    f32x4 acc[4][4] = {};

    for (int it = it0; it < it1; ++it) {
        int k0 = it * BK;
        {
            const uint4* Ag = (const uint4*)(A + (size_t)(m0 + srow) * KX + k0 + spart * 32);
            uint4 av[4];
#pragma unroll
            for (int i = 0; i < 4; ++i) av[i] = Ag[i];
#pragma unroll
            for (int i = 0; i < 4; ++i)
                *(uint4*)&As[srow][spart * 32 + i * 8] = av[i];
        }
        {
            const uint4* Bg = (const uint4*)(B + (size_t)(n0 + srow) * KX + k0 + spart * 32);
            uint4 bv[4];
#pragma unroll
            for (int i = 0; i < 4; ++i) bv[i] = Bg[i];
#pragma unroll
            for (int i = 0; i < 4; ++i)
                *(uint4*)&Bs[srow][spart * 32 + i * 8] = bv[i];
        }
        __syncthreads();

#pragma unroll
        for (int ks = 0; ks < 2; ++ks) {
            int kk = ks * 32 + fq * 8;
            bf16x8 af[4], bf[4];
#pragma unroll
            for (int i = 0; i < 4; ++i)
                af[i] = *(const bf16x8*)&As[wm + i * 16 + fl][kk];
#pragma unroll
            for (int j = 0; j < 4; ++j)
                bf[j] = *(const bf16x8*)&Bs[wn + j * 16 + fl][kk];
#pragma unroll
            for (int i = 0; i < 4; ++i)
#pragma unroll
                for (int j = 0; j < 4; ++j)
                    acc[i][j] = __builtin_amdgcn_mfma_f32_16x16x32_bf16(
                        af[i], bf[j], acc[i][j], 0, 0, 0);
        }
        __syncthreads();
    }

#pragma unroll
    for (int i = 0; i < 4; ++i)
#pragma unroll
        for (int j = 0; j < 4; ++j)
#pragma unroll
            for (int r = 0; r < 4; ++r) {
                int m = m0 + wm + i * 16 + fq * 4 + r;
                int n = n0 + wn + j * 16 + fl;
                partials[((size_t)z * NN + m) * NZ + n] = acc[i][j][r];
            }
}

// Z = sum_z partials
__global__ void k_reduceZ(const float* __restrict__ partials, float* __restrict__ Z) {
    int idx = blockIdx.x * 256 + threadIdx.x;
    if (idx >= NN * NZ) return;
    float s = 0.f;
#pragma unroll
    for (int zz = 0; zz < SPLITS; ++zz) s += partials[(size_t)zz * NN * NZ + idx];
    Z[idx] = s;
}

// h[i][j] = relu(Z[i][j] + sum_s A2[i][s]*Z[s][H2+j] + b[j]),  j covered 3x256
__global__ void k_fuse(const float* __restrict__ A2, const float* __restrict__ Z,
                       const float* __restrict__ b, float* __restrict__ h) {
    int i = blockIdx.x;
    int t = threadIdx.x;
    __shared__ float row[NN];
    row[t] = A2[(size_t)i * NN + t];
    row[t + 256] = A2[(size_t)i * NN + 256 + t];
    __syncthreads();
    float s0 = 0.f, s1 = 0.f, s2 = 0.f;
    for (int s = 0; s < NN; ++s) {
        float a = row[s];
        if (a != 0.f) {
            const float* zr = Z + (size_t)s * NZ + H2;
            s0 += a * zr[t];
            s1 += a * zr[t + 256];
            s2 += a * zr[t + 512];
        }
    }
    const float* zl = Z + (size_t)i * NZ;
    float v0 = zl[t] + s0 + b[t];
    float v1 = zl[t + 256] + s1 + b[t + 256];
    float v2 = zl[t + 512] + s2 + b[t + 512];
    float* hr = h + (size_t)i * H2;
    hr[t] = v0 > 0.f ? v0 : 0.f;
    hr[t + 256] = v1 > 0.f ? v1 : 0.f;
    hr[t + 512] = v2 > 0.f ? v2 : 0.f;
}

// encoded[m][e] = h[m] . W_e3[e] + b_e3[e]
__global__ void k_enc(const float* __restrict__ h, const float* __restrict__ W,
                      const float* __restrict__ b, float* __restrict__ out) {
    int m = blockIdx.x, e = threadIdx.x;
    const float4* hr = (const float4*)(h + (size_t)m * H2);
    const float4* wr = (const float4*)(W + (size_t)e * H2);
    float s = 0.f;
#pragma unroll 4
    for (int i = 0; i < H2 / 4; ++i) {
        float4 a = hr[i];
        float4 w = wr[i];
        s += a.x * w.x + a.y * w.y + a.z * w.z + a.w * w.w;
    }
    out[(size_t)m * EMB + e] = s + b[e];
}

// hd_b[m][j] = bf16(relu(enc[m] . W_d1[j] + b_d1[j]))
__global__ void k_dec1(const float* __restrict__ enc, const float* __restrict__ W,
                       const float* __restrict__ b, __bf16* __restrict__ hd) {
    int m = blockIdx.x;
    __shared__ float er[EMB];
    if (threadIdx.x < EMB) er[threadIdx.x] = enc[(size_t)m * EMB + threadIdx.x];
    __syncthreads();
    for (int j = threadIdx.x; j < H2; j += 256) {
        const float4* wr = (const float4*)(W + (size_t)j * EMB);
        float s = 0.f;
#pragma unroll
        for (int i = 0; i < EMB / 4; ++i) {
            float4 w = wr[i];
            s += w.x * er[4 * i] + w.y * er[4 * i + 1] + w.z * er[4 * i + 2] +
                 w.w * er[4 * i + 3];
        }
        float v = s + b[j];
        hd[(size_t)m * H2 + j] = (__bf16)(v > 0.f ? v : 0.f);
    }
}

// ---------------- gemm_wide: full-M decoder GEMM, B (W_d3 fp32) read once ----------------
// C[m][n] = sum_k A[m][k]*B[n][k] + bias[n];  A=[512][H2] bf16, B=[IN_DIM][H2] fp32.
// Block owns n-tile of 64; all M=512 staged in LDS per K-step.

#define WBN 64
#define WBK 64
#define ALD 68   // As row stride (bf16): 136 B = 34 dwords -> conflict-free frag reads
#define BLD 72

__global__ __launch_bounds__(256, 2) void gemm_wide(
        const __bf16* __restrict__ A, const float* __restrict__ B,
        const float* __restrict__ bias, float* __restrict__ C) {
    __shared__ __align__(16) __bf16 As[NN * ALD];
    __shared__ __align__(16) __bf16 Bs[WBN * BLD];

    const int tid = threadIdx.x;
    const int n0 = blockIdx.x * WBN;
    const int wave = tid >> 6, lane = tid & 63;
    const int fl = lane & 15, fq = lane >> 4;
    const int wm = wave * 128;

    const int brow = tid >> 2;          // 0..63
    const int bcol = (tid & 3) * 16;    // 0,16,32,48
    const int gn = n0 + brow;
    const bool bok = gn < IN_DIM;

    f32x4 acc[8][4] = {};

    for (int it = 0; it < H2 / WBK; ++it) {
        int k0 = it * WBK;
        // stage A: 4096 granules of 8 bf16, 16 per thread
#pragma unroll
        for (int q = 0; q < 16; ++q) {
            int g = tid + 256 * q;
            int r = g >> 3, c8 = (g & 7) * 8;
            uint4 v = *(const uint4*)(A + (size_t)r * H2 + k0 + c8);
            *(uint4*)&As[r * ALD + c8] = v;
        }
        // stage B: row gn, 16 floats -> bf16
        {
            __align__(16) __bf16 bl[16];
            if (bok) {
                const float4* bg = (const float4*)(B + (size_t)gn * H2 + k0 + bcol);
#pragma unroll
                for (int j = 0; j < 4; ++j) {
                    float4 f = bg[j];
                    bl[4 * j] = (__bf16)f.x;
                    bl[4 * j + 1] = (__bf16)f.y;
                    bl[4 * j + 2] = (__bf16)f.z;
                    bl[4 * j + 3] = (__bf16)f.w;
                }
            } else {
#pragma unroll
                for (int j = 0; j < 16; ++j) bl[j] = (__bf16)0.f;
            }
            *(uint4*)&Bs[brow * BLD + bcol] = *(uint4*)&bl[0];
            *(uint4*)&Bs[brow * BLD + bcol + 8] = *(uint4*)&bl[8];
        }
        __syncthreads();

#pragma unroll
        for (int ks = 0; ks < 2; ++ks) {
            int kk = ks * 32 + fq * 8;
            bf16x8 bfr[4];
#pragma unroll
            for (int j = 0; j < 4; ++j)
                bfr[j] = *(const bf16x8*)&Bs[(j * 16 + fl) * BLD + kk];
#pragma unroll
            for (int i = 0; i < 8; ++i) {
                bf16x8 afr = *(const bf16x8*)&As[(wm + i * 16 + fl) * ALD + kk];
#pragma unroll
                for (int j = 0; j < 4; ++j)
                    acc[i][j] = __builtin_amdgcn_mfma_f32_16x16x32_bf16(
                        afr, bfr[j], acc[i][j], 0, 0, 0);
            }
        }
        __syncthreads();
    }

#pragma unroll
    for (int i = 0; i < 8; ++i)
#pragma unroll
        for (int j = 0; j < 4; ++j)
#pragma unroll
            for (int r = 0; r < 4; ++r) {
                int m = wm + i * 16 + fq * 4 + r;
                int n = n0 + j * 16 + fl;
                if (n < IN_DIM)
                    C[(size_t)m * IN_DIM + n] = acc[i][j][r] + bias[n];
            }
}

// ---------------- launch ----------------

extern "C" void kernel_launch(void* const* d_in, const int* in_sizes, int n_in,
                              void* d_out, int out_size, void* d_ws, size_t ws_size,
                              hipStream_t stream) {
    const float* x = (const float*)d_in[0];
    const int* esrc = (const int*)d_in[1];
    const int* edst = (const int*)d_in[2];
    const float* W_e2 = (const float*)d_in[3];
    const float* b_e2 = (const float*)d_in[4];
    const float* W_e3 = (const float*)d_in[5];
    const float* b_e3 = (const float*)d_in[6];
    const float* W_d1 = (const float*)d_in[7];
    const float* b_d1 = (const float*)d_in[8];
    const float* W_d3 = (const float*)d_in[9];
    const float* b_d3 = (const float*)d_in[10];
    float* out = (float*)d_out;

    char* w = (char*)d_ws;
    auto alloc = [&](size_t bytes) {
        char* p = w;
        w += (bytes + 255) & ~(size_t)255;
        return p;
    };
    __bf16* xb = (__bf16*)alloc((size_t)NN * KX * 2);          // 18.4 MB
    __bf16* Wb = (__bf16*)alloc((size_t)NZ * KX * 2);          // 55.2 MB
    float* partials = (float*)alloc((size_t)SPLITS * NN * NZ * 4); // 50.3 MB
    float* Z = (float*)alloc((size_t)NN * NZ * 4);             // 3.1 MB
    float* Adj = (float*)alloc((size_t)NN * NN * 4);           // 1 MB
    float* A2f = (float*)alloc((size_t)NN * NN * 4);           // 1 MB
    int* cnt = (int*)alloc(NN * 4);
    float* invdeg = (float*)alloc(NN * 4);
    float* h = (float*)alloc((size_t)NN * H2 * 4);
    __bf16* hd_b = (__bf16*)alloc((size_t)NN * H2 * 2);

    // adjacency
    k_zero_int<<<2, 256, 0, stream>>>(cnt, NN);
    k_zero_f4<<<256, 256, 0, stream>>>((float4*)Adj, NN * NN / 4);
    k_deg<<<NE / 256, 256, 0, stream>>>(edst, cnt);
    k_invdeg<<<2, 256, 0, stream>>>(cnt, invdeg);
    k_scatter<<<NE / 256, 256, 0, stream>>>(esrc, edst, invdeg, Adj);
    k_a2f<<<NN, 256, 0, stream>>>(Adj, A2f);

    // bf16 operands
    k_xb<<<(int)(((size_t)NN * KX + 255) / 256), 256, 0, stream>>>(x, xb);
    k_wb<<<(int)(((size_t)NZ * KX + 255) / 256), 256, 0, stream>>>(W_e2, Wb);

    // Z = xb @ Wb^T (split-K)
    dim3 gz(NN / BM, NZ / BN, SPLITS);
    gemm_splitk<<<gz, 256, 0, stream>>>(xb, Wb, partials);
    k_reduceZ<<<(NN * NZ) / 256, 256, 0, stream>>>(partials, Z);

    // h = relu(Z_L + A2 @ Z_R + b_e2)
    k_fuse<<<NN, 256, 0, stream>>>(A2f, Z, b_e2, h);

    // encoded
    k_enc<<<NN, EMB, 0, stream>>>(h, W_e3, b_e3, out);

    // decoder hidden
    k_dec1<<<NN, 256, 0, stream>>>(out, W_d1, b_d1, hd_b);

    // decoded = hd @ W_d3^T + b_d3
    gemm_wide<<<(IN_DIM + WBN - 1) / WBN, 256, 0, stream>>>(
        hd_b, W_d3, b_d3, out + (size_t)NN * EMB);
}